// Round 4
// baseline (1670.447 us; speedup 1.0000x reference)
//
#include <hip/hip_runtime.h>

typedef unsigned short ushort_t;
typedef unsigned int uint32;
typedef __attribute__((ext_vector_type(8))) short short8;
typedef __attribute__((ext_vector_type(4))) short short4v;
typedef __attribute__((ext_vector_type(4))) float floatx4;

#define B_    128
#define T_    512
#define H_    256
#define H2_   512
#define LIN_  200
#define LINP_ 224
#define G4_   1024
#define SP_   58
#define BT_   (B_*T_)

// ---------- ws layout (bytes) ----------
#define OFF_LS     0UL          // int  [B,T]      262144
#define OFF_LP     262144UL     // int  [B,T]      262144
#define OFF_WID    524288UL     // int  [B,T]      262144
#define OFF_INV    786432UL     // f32  [B,T]      262144
#define OFF_POSW   1212416UL    // f32  [32][200]   25600
#define OFF_WLW    1238016UL    // f32  [8][200]     6400
#define OFF_BIASG  1244416UL    // f32  [1024]       4096
#define OFF_WHH    1248512UL    // fp8  [1024][256] 262144
#define OFF_WIH    1772800UL    // bf16 [1024][224] 458752
#define OFF_WENC   2231552UL    // bf16 [200][512]  204800
#define OFF_COMBW  2436352UL    // bf16 [58][768]    89088
#define OFF_ECW    2525440UL    // bf16 [65536][200] time-major rows (t*128+b)
#define OFF_Z      28739840UL   // bf16 [65536][224] time-major rows
#define OFF_GPERM  58099968UL   // bf16 swizzled [512][8][8][8][64][4]
#define OFF_VBF    192317696UL  // bf16 [65536][768] time-major rows (0:256 hs, 256:768 enc)

__device__ __forceinline__ ushort_t f2bf(float x){
  uint32 u = __float_as_uint(x);
  u += 0x7fffu + ((u >> 16) & 1u);
  return (ushort_t)(u >> 16);
}
__device__ __forceinline__ float bf2f(ushort_t v){
  return __uint_as_float(((uint32)v) << 16);
}
// fast sigmoid/tanh (exp2-based __expf + v_rcp); |err| ~1e-5, way inside bf16
__device__ __forceinline__ float fsig(float x){
  return __builtin_amdgcn_rcpf(1.0f + __expf(-x));
}
__device__ __forceinline__ float ftanh(float x){
  return 1.0f - 2.0f * __builtin_amdgcn_rcpf(1.0f + __expf(2.0f * x));
}

// ---------- scan: last_sep / wordlen / last_pos (b-major aux arrays) ----------
__global__ void k_scan(const int* __restrict__ sep, const int* __restrict__ pos_ids,
                       int* __restrict__ ls, int* __restrict__ lp,
                       int* __restrict__ wid, float* __restrict__ inv){
  int b = blockIdx.x * 64 + threadIdx.x;
  if (b >= B_) return;
  int run = 0;
  for (int t = 0; t < T_; t++){
    int l = (t == 0) ? 0 : run;
    if (sep[b*T_ + t] > 0) run = t;
    int wlen = t - l;
    int wsv  = (wlen < 1) ? 1 : wlen;
    ls[b*T_ + t]  = l;
    lp[b*T_ + t]  = pos_ids[b*T_ + l];
    wid[b*T_ + t] = (wsv > 7) ? 7 : wsv;
    inv[b*T_ + t] = 1.0f / (float)wsv;
  }
}

// ---------- enc -> bf16 into vbf[t*128+b][256:768] ----------
__global__ __launch_bounds__(256) void k_encbf(const float* __restrict__ enc, ushort_t* __restrict__ vbf){
  long row = blockIdx.x;           // b*512 + t (matches enc layout)
  int b = (int)(row >> 9), t = (int)(row & (T_-1));
  int c = threadIdx.x;
  const float* e = enc + row * H2_;
  ushort_t* v = vbf + ((long)t * B_ + b) * 768 + 256;
  v[c]       = f2bf(e[c]);
  v[c + 256] = f2bf(e[c + 256]);
}

// ---------- small precomputes / weight conversions ----------
__global__ __launch_bounds__(256) void k_small(
    const float* __restrict__ pos_emb, const float* __restrict__ wl_emb,
    const float* __restrict__ fcW, const float* __restrict__ W_ih,
    const float* __restrict__ W_hh, const float* __restrict__ b_ih,
    const float* __restrict__ b_hh, const float* __restrict__ combW,
    float* __restrict__ posW, float* __restrict__ wlW, float* __restrict__ biasg,
    char* __restrict__ whh8, ushort_t* __restrict__ wih,
    ushort_t* __restrict__ wenc, ushort_t* __restrict__ combwb){
  int idx = blockIdx.x * 256 + threadIdx.x;
  if (idx < 6400){
    int p = idx / 200, l = idx % 200;
    float s = 0.f;
    for (int d = 0; d < 50; d++) s += pos_emb[p*50 + d] * fcW[l*582 + d];
    posW[idx] = s; return;
  }
  idx -= 6400;
  if (idx < 1600){
    int w = idx / 200, l = idx % 200;
    float s = 0.f;
    for (int d = 0; d < 20; d++) s += wl_emb[w*20 + d] * fcW[l*582 + 562 + d];
    wlW[idx] = s; return;
  }
  idx -= 1600;
  if (idx < 1024){ biasg[idx] = b_ih[idx] + b_hh[idx]; return; }
  idx -= 1024;
  if (idx < 262144){
    int p8 = __builtin_amdgcn_cvt_pk_fp8_f32(W_hh[idx], W_hh[idx], 0, false);
    whh8[idx] = (char)(p8 & 0xff);
    return;
  }
  idx -= 262144;
  if (idx < 229376){
    int n = idx / 224, k = idx % 224;
    wih[idx] = (k < 200) ? f2bf(W_ih[n*200 + k]) : (ushort_t)0;
    return;
  }
  idx -= 229376;
  if (idx < 102400){
    int l = idx / 512, c = idx % 512;
    wenc[idx] = f2bf(fcW[l*582 + 50 + c]); return;
  }
  idx -= 102400;
  if (idx < 44544){ combwb[idx] = f2bf(combW[idx]); return; }
}

// ---------- generic 64x64 bf16 MFMA GEMM: C[m,n] = sum_k A[m,k]*B[n,k] ----------
// EPI 0: bf16 out [m][Nvalid]
// EPI 1: +bias, bf16 out swizzled Gperm fragment layout (m is time-major t*128+b)
// EPI 2: masked fp32 logits, m time-major -> out b-major [b*T+t][58]
template<int EPI>
__global__ __launch_bounds__(256) void k_gemm(
    const ushort_t* __restrict__ A, long lda,
    const ushort_t* __restrict__ Bm, int K, int Nvalid,
    void* __restrict__ Cout, const float* __restrict__ bias, const int* __restrict__ len){
  __shared__ __attribute__((aligned(16))) ushort_t As[64][48];
  __shared__ __attribute__((aligned(16))) ushort_t Bs[64][48];
  int tid  = threadIdx.x;
  int lane = tid & 63, wave = tid >> 6;
  int u = lane & 15, quad = lane >> 4;
  int mh = wave >> 1, nh = wave & 1;
  long m0 = (long)blockIdx.x * 64;
  int  n0 = blockIdx.y * 64;
  int lrow = tid >> 2;
  int lcol = (tid & 3) * 8;
  const ushort_t* Arow = A + (m0 + lrow) * lda + lcol;
  bool bvalid = (n0 + lrow) < Nvalid;
  const ushort_t* Brow = Bm + (long)(n0 + lrow) * K + lcol;
  floatx4 acc[2][2] = {};
  for (int k = 0; k < K; k += 32){
    short8 av = *(const short8*)(const void*)(Arow + k);
    short8 bv = {0,0,0,0,0,0,0,0};
    if (bvalid) bv = *(const short8*)(const void*)(Brow + k);
    __syncthreads();
    *(short8*)(void*)&As[lrow][lcol] = av;
    *(short8*)(void*)&Bs[lrow][lcol] = bv;
    __syncthreads();
    short8 a0 = *(const short8*)(const void*)&As[mh*32 + u][quad*8];
    short8 a1 = *(const short8*)(const void*)&As[mh*32 + 16 + u][quad*8];
    short8 b0 = *(const short8*)(const void*)&Bs[nh*32 + u][quad*8];
    short8 b1 = *(const short8*)(const void*)&Bs[nh*32 + 16 + u][quad*8];
    acc[0][0] = __builtin_amdgcn_mfma_f32_16x16x32_bf16(a0, b0, acc[0][0], 0, 0, 0);
    acc[0][1] = __builtin_amdgcn_mfma_f32_16x16x32_bf16(a0, b1, acc[0][1], 0, 0, 0);
    acc[1][0] = __builtin_amdgcn_mfma_f32_16x16x32_bf16(a1, b0, acc[1][0], 0, 0, 0);
    acc[1][1] = __builtin_amdgcn_mfma_f32_16x16x32_bf16(a1, b1, acc[1][1], 0, 0, 0);
  }
  if (EPI == 1){
    #pragma unroll
    for (int mi = 0; mi < 2; mi++){
      #pragma unroll
      for (int ni = 0; ni < 2; ni++){
        long mm = m0 + mh*32 + mi*16 + quad*4;     // r=0 row; 4 r's = 4 consecutive b
        int n = n0 + nh*32 + ni*16 + u;
        float bv = bias[n];
        int t = (int)(mm >> 7);
        int b = (int)(mm & 127);
        int bg = b >> 4, q2 = (b >> 2) & 3;
        int g = n >> 8, j = n & 255, uu = j & 15, jt = j >> 4, ww = jt & 7, jI = jt >> 3;
        int ti = g*2 + jI;
        long idx = ((((long)t*8 + bg)*8 + ww)*8 + ti)*256 + (q2*16 + uu)*4;
        short4v pk;
        #pragma unroll
        for (int r = 0; r < 4; r++) pk[r] = (short)f2bf(acc[mi][ni][r] + bv);
        *(short4v*)(void*)((ushort_t*)Cout + idx) = pk;
      }
    }
  } else {
    for (int mi = 0; mi < 2; mi++){
      for (int ni = 0; ni < 2; ni++){
        for (int r = 0; r < 4; r++){
          long m = m0 + mh*32 + mi*16 + quad*4 + r;
          int  n = n0 + nh*32 + ni*16 + u;
          float v = acc[mi][ni][r];
          if (EPI == 0){
            if (n < Nvalid) ((ushort_t*)Cout)[m * Nvalid + n] = f2bf(v);
          } else {
            if (n < Nvalid){
              int t = (int)(m >> 7); int b = (int)(m & 127);
              float o = (t < len[b]) ? v : 0.0f;
              if (t == 0 && n == 0) o = -1e30f;
              ((float*)Cout)[((long)b * T_ + t) * SP_ + n] = o;
            }
          }
        }
      }
    }
  }
}

// ---------- exclusive cumsum over t, in place on E (bf16, time-major rows) ----------
__global__ __launch_bounds__(256) void k_cum200(ushort_t* __restrict__ E){
  int b = blockIdx.x;
  int c = threadIdx.x;
  if (c >= LIN_) return;
  float acc = 0.f;
  ushort_t* p = E + (long)b * LIN_ + c;      // row (t*128+b)
  const long rs = (long)B_ * LIN_;           // per-t stride
  for (int t0 = 0; t0 < T_; t0 += 16){
    float vv[16];
    #pragma unroll
    for (int i = 0; i < 16; i++) vv[i] = bf2f(p[i*rs]);
    #pragma unroll
    for (int i = 0; i < 16; i++){ p[i*rs] = f2bf(acc); acc += vv[i]; }
    p += 16*rs;
  }
}

// ---------- z = tanh((CW[t]-CW[ls])*inv + posW + wlW + b), t=0 -> 0, pad K to 224 ----------
__global__ __launch_bounds__(256) void k_z(
    const ushort_t* __restrict__ CW, const int* __restrict__ ls, const int* __restrict__ lp,
    const int* __restrict__ wid, const float* __restrict__ inv,
    const float* __restrict__ posW, const float* __restrict__ wlW,
    const float* __restrict__ fcb, ushort_t* __restrict__ zbf){
  int m = blockIdx.x;               // time-major row t*128+b
  int l = threadIdx.x;
  if (l >= LINP_) return;
  int t = m >> 7;
  int b = m & 127;
  int ar = b * T_ + t;              // b-major aux index
  ushort_t o = 0;
  if (t != 0 && l < LIN_){
    int lsv = ls[ar];
    float x = bf2f(CW[(long)m * LIN_ + l]) - bf2f(CW[((long)lsv * B_ + b) * LIN_ + l]);
    x = x * inv[ar] + posW[lp[ar]*LIN_ + l] + wlW[wid[ar]*LIN_ + l] + fcb[l];
    o = f2bf(ftanh(x));
  }
  zbf[(long)m * LINP_ + l] = o;
}

// ---------- LSTM recurrence: 8 independent workgroups, half-step software pipeline ----------
// 512 threads = 8 waves. Wave w owns hidden tiles {w, w+8} x 4 gates (ti = g*2 + jtI).
// Per step: two lgkm-only barriers split h into lo/hi halves; step-t epilogue VALU
// issues after step-(t+1)'s independent kc0-3 MFMAs -> transcendentals hide under
// the matrix pipe. Raw s_barrier + manual lgkmcnt(0): global stores never drain.
__global__ __launch_bounds__(512, 2) void k_rec(
    const ushort_t* __restrict__ Gperm, const char* __restrict__ whh8,
    ushort_t* __restrict__ vbf){
  int bg   = blockIdx.x;
  int tid  = threadIdx.x;
  int lane = tid & 63, w = tid >> 6;
  int u = lane & 15, quad = lane >> 4;
  __shared__ __attribute__((aligned(16))) char h8[2][16][264];

  // W_hh fp8 fragments: tile ti=g*2+jtI -> gate g, hidden tile w+8*jtI; pinned.
  long wfrag[8][8];
  #pragma unroll
  for (int g = 0; g < 4; g++){
    #pragma unroll
    for (int jtI = 0; jtI < 2; jtI++){
      int grow = g*256 + (w + jtI*8)*16 + u;
      #pragma unroll
      for (int kc = 0; kc < 8; kc++){
        long v = *(const long*)(const void*)(whh8 + (long)grow*256 + kc*32 + quad*8);
        asm volatile("" : "+v"(v));
        wfrag[g*2+jtI][kc] = v;
      }
    }
  }
  float c_reg[2][4] = {{0.f,0.f,0.f,0.f},{0.f,0.f,0.f,0.f}};

  const ushort_t* gp0 = Gperm + ((long)(bg*8 + w))*2048 + (long)lane*4;
  short4v gbuf[8];
  #pragma unroll
  for (int ti = 0; ti < 8; ti++) gbuf[ti] = *(const short4v*)(const void*)(gp0 + ti*256);

  ushort_t* vb = vbf + (long)bg*16*768;   // row t*128 + bg*16 + row
  floatx4 acc[2][8];

#define LGKM_BAR() do{ asm volatile("s_waitcnt lgkmcnt(0)" ::: "memory"); \
                       __builtin_amdgcn_s_barrier(); } while(0)

  // consume gbuf (= Gperm step) into acc slot S, then prefetch Gperm step tn
#define ACCINIT(S, tn) do{ \
    _Pragma("unroll") for (int ti = 0; ti < 8; ti++){ \
      _Pragma("unroll") for (int r = 0; r < 4; r++) \
        acc[S][ti][r] = bf2f((ushort_t)gbuf[ti][r]); } \
    if ((tn) < T_){ const ushort_t* gp = gp0 + (long)(tn)*131072; \
      _Pragma("unroll") for (int ti = 0; ti < 8; ti++) \
        gbuf[ti] = *(const short4v*)(const void*)(gp + ti*256); } \
  }while(0)

  // MFMA over K half: half=0 -> kc0-3 (h cols 0:128), half=1 -> kc4-7 (128:256)
#define MPHASE(S, par, half) do{ \
    long afv[4]; \
    _Pragma("unroll") for (int kc = 0; kc < 4; kc++) \
      afv[kc] = *(const long*)(const void*)&h8[par][u][(half)*128 + kc*32 + quad*8]; \
    _Pragma("unroll") for (int ti = 0; ti < 8; ti++){ \
      _Pragma("unroll") for (int kc = 0; kc < 4; kc++) \
        acc[S][ti] = __builtin_amdgcn_mfma_f32_16x16x32_fp8_fp8( \
            afv[kc], wfrag[ti][(half)*4 + kc], acc[S][ti], 0, 0, 0); } \
  }while(0)

  // epilogue for half jtI of step t; write h8[parN] (if WRH8) + vbf
#define EPIL(S, jtI, t, parN, WRH8) do{ \
    int j = (w + (jtI)*8)*16 + u; \
    ushort_t* vrow = vb + (long)(t)*B_*768; \
    _Pragma("unroll") for (int r = 0; r < 4; r++){ \
      float iv = fsig (acc[S][0 + (jtI)][r]); \
      float fv = fsig (acc[S][2 + (jtI)][r]); \
      float gv = ftanh(acc[S][4 + (jtI)][r]); \
      float ov = fsig (acc[S][6 + (jtI)][r]); \
      float c  = fv * c_reg[jtI][r] + iv * gv; \
      c_reg[jtI][r] = c; \
      float h  = ov * ftanh(c); \
      int row = quad*4 + r; \
      if (WRH8){ int p8 = __builtin_amdgcn_cvt_pk_fp8_f32(h, h, 0, false); \
                 h8[parN][row][j] = (char)(p8 & 0xff); } \
      vrow[(long)row*768 + j] = f2bf(h); \
    } \
  }while(0)

#define STEPP(SC, SN, t) do{ \
    MPHASE(SC, ((t)-1)&1, 1);      /* Mhi(t) */ \
    EPIL(SC, 0, t, (t)&1, 1);      /* Elo(t) -> h8[t&1] lo */ \
    LGKM_BAR();                    /* BL(t) */ \
    ACCINIT(SN, (t)+2);            /* ACC(t+1), prefetch G(t+2) */ \
    MPHASE(SN, (t)&1, 0);          /* Mlo(t+1) */ \
    EPIL(SC, 1, t, (t)&1, 1);      /* Ehi(t) -> h8[t&1] hi (hides under Mlo) */ \
    LGKM_BAR();                    /* BU(t) */ \
  }while(0)

  // ---- prologue: t=0 has h(-1)=0, no MFMA ----
  ACCINIT(0, 1);                   // acc0 = G(0), prefetch G(1)
  EPIL(0, 0, 0, 0, 1);             // Elo(0) -> h8[0] lo
  LGKM_BAR();                      // BL(0)
  ACCINIT(1, 2);                   // acc1 = G(1), prefetch G(2)
  MPHASE(1, 0, 0);                 // Mlo(1) reads h8[0] lo
  EPIL(0, 1, 0, 0, 1);             // Ehi(0) -> h8[0] hi
  LGKM_BAR();                      // BU(0)
  // ---- steady state: t = 1..510 ----
  for (int t = 1; t <= 509; t += 2){
    STEPP(1, 0, t);
    STEPP(0, 1, t+1);
  }
  // ---- tail: t=511 ----
  MPHASE(1, 0, 1);                 // Mhi(511) reads h8[0] hi
  EPIL(1, 0, 511, 1, 0);           // vbf only
  EPIL(1, 1, 511, 1, 0);
#undef LGKM_BAR
#undef ACCINIT
#undef MPHASE
#undef EPIL
#undef STEPP
}

extern "C" void kernel_launch(void* const* d_in, const int* in_sizes, int n_in,
                              void* d_out, int out_size, void* d_ws, size_t ws_size,
                              hipStream_t stream){
  (void)in_sizes; (void)n_in; (void)out_size; (void)ws_size;
  const float* enc     = (const float*)d_in[0];
  const int*   sep     = (const int*)  d_in[1];
  const int*   pos_ids = (const int*)  d_in[2];
  const int*   len     = (const int*)  d_in[3];
  const float* pos_emb = (const float*)d_in[4];
  const float* wl_emb  = (const float*)d_in[5];
  const float* fcW     = (const float*)d_in[6];
  const float* fcb     = (const float*)d_in[7];
  const float* W_ih    = (const float*)d_in[8];
  const float* W_hh    = (const float*)d_in[9];
  const float* b_ih    = (const float*)d_in[10];
  const float* b_hh    = (const float*)d_in[11];
  const float* combW   = (const float*)d_in[12];

  char* ws = (char*)d_ws;
  int*      ls    = (int*)     (ws + OFF_LS);
  int*      lp    = (int*)     (ws + OFF_LP);
  int*      wid   = (int*)     (ws + OFF_WID);
  float*    inv   = (float*)   (ws + OFF_INV);
  float*    posW  = (float*)   (ws + OFF_POSW);
  float*    wlW   = (float*)   (ws + OFF_WLW);
  float*    biasg = (float*)   (ws + OFF_BIASG);
  char*     whh8  = (char*)    (ws + OFF_WHH);
  ushort_t* wih   = (ushort_t*)(ws + OFF_WIH);
  ushort_t* wenc  = (ushort_t*)(ws + OFF_WENC);
  ushort_t* combwb= (ushort_t*)(ws + OFF_COMBW);
  ushort_t* ecw   = (ushort_t*)(ws + OFF_ECW);
  ushort_t* zbf   = (ushort_t*)(ws + OFF_Z);
  ushort_t* gperm = (ushort_t*)(ws + OFF_GPERM);
  ushort_t* vbf   = (ushort_t*)(ws + OFF_VBF);

  k_scan<<<2, 64, 0, stream>>>(sep, pos_ids, ls, lp, wid, inv);
  k_encbf<<<BT_, 256, 0, stream>>>(enc, vbf);
  k_small<<<2530, 256, 0, stream>>>(pos_emb, wl_emb, fcW, W_ih, W_hh, b_ih, b_hh, combW,
                                    posW, wlW, biasg, whh8, wih, wenc, combwb);
  // E = enc @ Wenc^T  (rows time-major)
  k_gemm<0><<<dim3(BT_/64, 4), 256, 0, stream>>>(vbf + 256, 768L, wenc, 512, LIN_, ecw, nullptr, nullptr);
  // exclusive cumsum over t (in place) -> CW
  k_cum200<<<B_, 256, 0, stream>>>(ecw);
  // z = tanh(...)
  k_z<<<BT_, 256, 0, stream>>>(ecw, ls, lp, wid, inv, posW, wlW, fcb, zbf);
  // Gperm = z @ W_ih^T + biases, written pre-swizzled for k_rec
  k_gemm<1><<<dim3(BT_/64, 16), 256, 0, stream>>>(zbf, (long)LINP_, wih, LINP_, G4_, gperm, biasg, nullptr);
  // LSTM recurrence (8 independent batch-group workgroups, LDS-only sync)
  k_rec<<<8, 512, 0, stream>>>(gperm, whh8, vbf);
  // logits = [hs, enc] @ combine_W^T, masked, scattered to b-major output
  k_gemm<2><<<dim3(BT_/64, 1), 256, 0, stream>>>(vbf, 768L, combwb, 768, SP_, d_out, nullptr, len);
}

// Round 5
// 1465.484 us; speedup vs baseline: 1.1399x; 1.1399x over previous
//
#include <hip/hip_runtime.h>

typedef unsigned short ushort_t;
typedef unsigned int uint32;
typedef __attribute__((ext_vector_type(8))) short short8;
typedef __attribute__((ext_vector_type(4))) short short4v;
typedef __attribute__((ext_vector_type(4))) float floatx4;
typedef __attribute__((ext_vector_type(2))) float float2v;
typedef __attribute__((ext_vector_type(8))) int intx8;

#define B_    128
#define T_    512
#define H_    256
#define H2_   512
#define LIN_  200
#define LINP_ 224
#define G4_   1024
#define SP_   58
#define BT_   (B_*T_)

// ---------- ws layout (bytes) ----------
#define OFF_LS     0UL          // int  [B,T]      262144
#define OFF_LP     262144UL     // int  [B,T]      262144
#define OFF_WID    524288UL     // int  [B,T]      262144
#define OFF_INV    786432UL     // f32  [B,T]      262144
#define OFF_POSW   1212416UL    // f32  [32][200]   25600
#define OFF_WLW    1238016UL    // f32  [8][200]     6400
#define OFF_BIASG  1244416UL    // f32  [1024]       4096
#define OFF_WHH    1248512UL    // fp8  [1024][256] 262144
#define OFF_WIH    1772800UL    // bf16 [1024][224] 458752
#define OFF_WENC   2231552UL    // bf16 [200][512]  204800
#define OFF_COMBW  2436352UL    // bf16 [58][768]    89088
#define OFF_ECW    2525440UL    // bf16 [65536][200] time-major rows (t*128+b)
#define OFF_Z      28739840UL   // bf16 [65536][224] time-major rows
#define OFF_GPERM  58099968UL   // bf16 swizzled [512][8][8][8][64][4]
#define OFF_VBF    192317696UL  // bf16 [65536][768] time-major rows (0:256 hs, 256:768 enc)

__device__ __forceinline__ ushort_t f2bf(float x){
  uint32 u = __float_as_uint(x);
  u += 0x7fffu + ((u >> 16) & 1u);
  return (ushort_t)(u >> 16);
}
__device__ __forceinline__ float bf2f(ushort_t v){
  return __uint_as_float(((uint32)v) << 16);
}
// fast sigmoid/tanh (exp2-based __expf + v_rcp); |err| ~1e-5, way inside bf16
__device__ __forceinline__ float fsig(float x){
  return __builtin_amdgcn_rcpf(1.0f + __expf(-x));
}
__device__ __forceinline__ float ftanh(float x){
  return 1.0f - 2.0f * __builtin_amdgcn_rcpf(1.0f + __expf(2.0f * x));
}

// ---------- scan: last_sep / wordlen / last_pos (b-major aux arrays) ----------
__global__ void k_scan(const int* __restrict__ sep, const int* __restrict__ pos_ids,
                       int* __restrict__ ls, int* __restrict__ lp,
                       int* __restrict__ wid, float* __restrict__ inv){
  int b = blockIdx.x * 64 + threadIdx.x;
  if (b >= B_) return;
  int run = 0;
  for (int t = 0; t < T_; t++){
    int l = (t == 0) ? 0 : run;
    if (sep[b*T_ + t] > 0) run = t;
    int wlen = t - l;
    int wsv  = (wlen < 1) ? 1 : wlen;
    ls[b*T_ + t]  = l;
    lp[b*T_ + t]  = pos_ids[b*T_ + l];
    wid[b*T_ + t] = (wsv > 7) ? 7 : wsv;
    inv[b*T_ + t] = 1.0f / (float)wsv;
  }
}

// ---------- enc -> bf16 into vbf[t*128+b][256:768] ----------
__global__ __launch_bounds__(256) void k_encbf(const float* __restrict__ enc, ushort_t* __restrict__ vbf){
  long row = blockIdx.x;           // b*512 + t (matches enc layout)
  int b = (int)(row >> 9), t = (int)(row & (T_-1));
  int c = threadIdx.x;
  const float* e = enc + row * H2_;
  ushort_t* v = vbf + ((long)t * B_ + b) * 768 + 256;
  v[c]       = f2bf(e[c]);
  v[c + 256] = f2bf(e[c + 256]);
}

// ---------- small precomputes / weight conversions ----------
__global__ __launch_bounds__(256) void k_small(
    const float* __restrict__ pos_emb, const float* __restrict__ wl_emb,
    const float* __restrict__ fcW, const float* __restrict__ W_ih,
    const float* __restrict__ W_hh, const float* __restrict__ b_ih,
    const float* __restrict__ b_hh, const float* __restrict__ combW,
    float* __restrict__ posW, float* __restrict__ wlW, float* __restrict__ biasg,
    char* __restrict__ whh8, ushort_t* __restrict__ wih,
    ushort_t* __restrict__ wenc, ushort_t* __restrict__ combwb){
  int idx = blockIdx.x * 256 + threadIdx.x;
  if (idx < 6400){
    int p = idx / 200, l = idx % 200;
    float s = 0.f;
    for (int d = 0; d < 50; d++) s += pos_emb[p*50 + d] * fcW[l*582 + d];
    posW[idx] = s; return;
  }
  idx -= 6400;
  if (idx < 1600){
    int w = idx / 200, l = idx % 200;
    float s = 0.f;
    for (int d = 0; d < 20; d++) s += wl_emb[w*20 + d] * fcW[l*582 + 562 + d];
    wlW[idx] = s; return;
  }
  idx -= 1600;
  if (idx < 1024){ biasg[idx] = b_ih[idx] + b_hh[idx]; return; }
  idx -= 1024;
  if (idx < 262144){
    int p8 = __builtin_amdgcn_cvt_pk_fp8_f32(W_hh[idx], W_hh[idx], 0, false);
    whh8[idx] = (char)(p8 & 0xff);
    return;
  }
  idx -= 262144;
  if (idx < 229376){
    int n = idx / 224, k = idx % 224;
    wih[idx] = (k < 200) ? f2bf(W_ih[n*200 + k]) : (ushort_t)0;
    return;
  }
  idx -= 229376;
  if (idx < 102400){
    int l = idx / 512, c = idx % 512;
    wenc[idx] = f2bf(fcW[l*582 + 50 + c]); return;
  }
  idx -= 102400;
  if (idx < 44544){ combwb[idx] = f2bf(combW[idx]); return; }
}

// ---------- generic 64x64 bf16 MFMA GEMM: C[m,n] = sum_k A[m,k]*B[n,k] ----------
// EPI 0: bf16 out [m][Nvalid]
// EPI 1: +bias, bf16 out swizzled Gperm fragment layout (m is time-major t*128+b)
// EPI 2: masked fp32 logits, m time-major -> out b-major [b*T+t][58]
template<int EPI>
__global__ __launch_bounds__(256) void k_gemm(
    const ushort_t* __restrict__ A, long lda,
    const ushort_t* __restrict__ Bm, int K, int Nvalid,
    void* __restrict__ Cout, const float* __restrict__ bias, const int* __restrict__ len){
  __shared__ __attribute__((aligned(16))) ushort_t As[64][48];
  __shared__ __attribute__((aligned(16))) ushort_t Bs[64][48];
  int tid  = threadIdx.x;
  int lane = tid & 63, wave = tid >> 6;
  int u = lane & 15, quad = lane >> 4;
  int mh = wave >> 1, nh = wave & 1;
  long m0 = (long)blockIdx.x * 64;
  int  n0 = blockIdx.y * 64;
  int lrow = tid >> 2;
  int lcol = (tid & 3) * 8;
  const ushort_t* Arow = A + (m0 + lrow) * lda + lcol;
  bool bvalid = (n0 + lrow) < Nvalid;
  const ushort_t* Brow = Bm + (long)(n0 + lrow) * K + lcol;
  floatx4 acc[2][2] = {};
  for (int k = 0; k < K; k += 32){
    short8 av = *(const short8*)(const void*)(Arow + k);
    short8 bv = {0,0,0,0,0,0,0,0};
    if (bvalid) bv = *(const short8*)(const void*)(Brow + k);
    __syncthreads();
    *(short8*)(void*)&As[lrow][lcol] = av;
    *(short8*)(void*)&Bs[lrow][lcol] = bv;
    __syncthreads();
    short8 a0 = *(const short8*)(const void*)&As[mh*32 + u][quad*8];
    short8 a1 = *(const short8*)(const void*)&As[mh*32 + 16 + u][quad*8];
    short8 b0 = *(const short8*)(const void*)&Bs[nh*32 + u][quad*8];
    short8 b1 = *(const short8*)(const void*)&Bs[nh*32 + 16 + u][quad*8];
    acc[0][0] = __builtin_amdgcn_mfma_f32_16x16x32_bf16(a0, b0, acc[0][0], 0, 0, 0);
    acc[0][1] = __builtin_amdgcn_mfma_f32_16x16x32_bf16(a0, b1, acc[0][1], 0, 0, 0);
    acc[1][0] = __builtin_amdgcn_mfma_f32_16x16x32_bf16(a1, b0, acc[1][0], 0, 0, 0);
    acc[1][1] = __builtin_amdgcn_mfma_f32_16x16x32_bf16(a1, b1, acc[1][1], 0, 0, 0);
  }
  if (EPI == 1){
    #pragma unroll
    for (int mi = 0; mi < 2; mi++){
      #pragma unroll
      for (int ni = 0; ni < 2; ni++){
        long mm = m0 + mh*32 + mi*16 + quad*4;     // r=0 row; 4 r's = 4 consecutive b
        int n = n0 + nh*32 + ni*16 + u;
        float bv = bias[n];
        int t = (int)(mm >> 7);
        int b = (int)(mm & 127);
        int bg = b >> 4, q2 = (b >> 2) & 3;
        int g = n >> 8, j = n & 255, uu = j & 15, jt = j >> 4, ww = jt & 7, jI = jt >> 3;
        int ti = g*2 + jI;
        long idx = ((((long)t*8 + bg)*8 + ww)*8 + ti)*256 + (q2*16 + uu)*4;
        short4v pk;
        #pragma unroll
        for (int r = 0; r < 4; r++) pk[r] = (short)f2bf(acc[mi][ni][r] + bv);
        *(short4v*)(void*)((ushort_t*)Cout + idx) = pk;
      }
    }
  } else {
    for (int mi = 0; mi < 2; mi++){
      for (int ni = 0; ni < 2; ni++){
        for (int r = 0; r < 4; r++){
          long m = m0 + mh*32 + mi*16 + quad*4 + r;
          int  n = n0 + nh*32 + ni*16 + u;
          float v = acc[mi][ni][r];
          if (EPI == 0){
            if (n < Nvalid) ((ushort_t*)Cout)[m * Nvalid + n] = f2bf(v);
          } else {
            if (n < Nvalid){
              int t = (int)(m >> 7); int b = (int)(m & 127);
              float o = (t < len[b]) ? v : 0.0f;
              if (t == 0 && n == 0) o = -1e30f;
              ((float*)Cout)[((long)b * T_ + t) * SP_ + n] = o;
            }
          }
        }
      }
    }
  }
}

// ---------- exclusive cumsum over t, in place on E (bf16, time-major rows) ----------
__global__ __launch_bounds__(256) void k_cum200(ushort_t* __restrict__ E){
  int b = blockIdx.x;
  int c = threadIdx.x;
  if (c >= LIN_) return;
  float acc = 0.f;
  ushort_t* p = E + (long)b * LIN_ + c;      // row (t*128+b)
  const long rs = (long)B_ * LIN_;           // per-t stride
  for (int t0 = 0; t0 < T_; t0 += 16){
    float vv[16];
    #pragma unroll
    for (int i = 0; i < 16; i++) vv[i] = bf2f(p[i*rs]);
    #pragma unroll
    for (int i = 0; i < 16; i++){ p[i*rs] = f2bf(acc); acc += vv[i]; }
    p += 16*rs;
  }
}

// ---------- z = tanh((CW[t]-CW[ls])*inv + posW + wlW + b), t=0 -> 0, pad K to 224 ----------
__global__ __launch_bounds__(256) void k_z(
    const ushort_t* __restrict__ CW, const int* __restrict__ ls, const int* __restrict__ lp,
    const int* __restrict__ wid, const float* __restrict__ inv,
    const float* __restrict__ posW, const float* __restrict__ wlW,
    const float* __restrict__ fcb, ushort_t* __restrict__ zbf){
  int m = blockIdx.x;               // time-major row t*128+b
  int l = threadIdx.x;
  if (l >= LINP_) return;
  int t = m >> 7;
  int b = m & 127;
  int ar = b * T_ + t;              // b-major aux index
  ushort_t o = 0;
  if (t != 0 && l < LIN_){
    int lsv = ls[ar];
    float x = bf2f(CW[(long)m * LIN_ + l]) - bf2f(CW[((long)lsv * B_ + b) * LIN_ + l]);
    x = x * inv[ar] + posW[lp[ar]*LIN_ + l] + wlW[wid[ar]*LIN_ + l] + fcb[l];
    o = f2bf(ftanh(x));
  }
  zbf[(long)m * LINP_ + l] = o;
}

// ---------- LSTM recurrence: 8 independent workgroups (one per 16-batch group) ----------
// 512 threads = 8 waves; wave w owns col tiles ti = g*2 + jtI (gate g, hidden tile w+8*jtI).
// MX-scaled fp8 MFMA K=128 (scales = 1.0 exactly): 16 MFMA/wave/step.
// h exchanged via fp8 LDS double buffer; single __syncthreads per step.
// hs written to vbf COALESCED (from LDS, one step delayed) -> tiny vmcnt drain at barrier.
__global__ __launch_bounds__(512, 2) void k_rec(
    const ushort_t* __restrict__ Gperm, const char* __restrict__ whh8,
    ushort_t* __restrict__ vbf){
  int bg   = blockIdx.x;
  int tid  = threadIdx.x;
  int lane = tid & 63, w = tid >> 6;
  int u = lane & 15, quad = lane >> 4;
  __shared__ __attribute__((aligned(16))) char h8[2][16][272];   // row stride 272 = 16*17
  for (int i = tid; i < (int)(sizeof(h8)/4); i += 512) ((int*)h8)[i] = 0;

  // W_hh fp8 B-fragments (MX K=128): B[col=u][k=quad*32+j], 32B/lane per chunk; pinned.
  intx8 wfx[8][2];
  #pragma unroll
  for (int g = 0; g < 4; g++){
    #pragma unroll
    for (int jtI = 0; jtI < 2; jtI++){
      int grow = g*256 + (w + jtI*8)*16 + u;
      #pragma unroll
      for (int kc = 0; kc < 2; kc++){
        intx8 v = *(const intx8*)(const void*)(whh8 + (long)grow*256 + kc*128 + quad*32);
        asm volatile("" : "+v"(v));
        wfx[g*2+jtI][kc] = v;
      }
    }
  }
  float c_reg[2][4] = {{0.f,0.f,0.f,0.f},{0.f,0.f,0.f,0.f}};

  const ushort_t* gp0 = Gperm + ((long)(bg*8 + w))*2048 + (long)lane*4;
  short4v gbuf[8];
  #pragma unroll
  for (int ti = 0; ti < 8; ti++) gbuf[ti] = *(const short4v*)(const void*)(gp0 + ti*256);

  for (int t = 0; t < T_; t++){
    // acc init from prefetched Gperm fragment (pre-barrier)
    floatx4 acc[8];
    #pragma unroll
    for (int ti = 0; ti < 8; ti++){
      #pragma unroll
      for (int r = 0; r < 4; r++)
        acc[ti][r] = bf2f((ushort_t)gbuf[ti][r]);
    }
    __syncthreads();                       // h8[t&1] = h(t-1) ready
    // MFMA first: get the matrix pipe going
    intx8 af0 = *(const intx8*)(const void*)&h8[t & 1][u][quad*32];
    intx8 af1 = *(const intx8*)(const void*)&h8[t & 1][u][128 + quad*32];
    #pragma unroll
    for (int ti = 0; ti < 8; ti++){
      acc[ti] = __builtin_amdgcn_mfma_scale_f32_16x16x128_f8f6f4(
          af0, wfx[ti][0], acc[ti], 0, 0, 0, 0x7F7F7F7F, 0, 0x7F7F7F7F);
      acc[ti] = __builtin_amdgcn_mfma_scale_f32_16x16x128_f8f6f4(
          af1, wfx[ti][1], acc[ti], 0, 0, 0, 0x7F7F7F7F, 0, 0x7F7F7F7F);
    }
    // coalesced vbf dump of h(t-1) from h8[t&1] (VALU/mem hides under MFMA pipe)
    if (t){
      ushort_t* vrow = vbf + ((long)(t-1) * B_ + bg*16) * 768;
      #pragma unroll
      for (int rr = 0; rr < 2; rr++){
        int row = w*2 + rr;
        uint32 p = *(const uint32*)(const void*)&h8[t & 1][row][lane*4];
        float2v lo = __builtin_amdgcn_cvt_pk_f32_fp8(p, false);
        float2v hi = __builtin_amdgcn_cvt_pk_f32_fp8(p, true);
        short4v pk;
        pk[0] = (short)f2bf(lo[0]); pk[1] = (short)f2bf(lo[1]);
        pk[2] = (short)f2bf(hi[0]); pk[3] = (short)f2bf(hi[1]);
        *(short4v*)(void*)&vrow[(long)row*768 + lane*4] = pk;
      }
    }
    // prefetch next Gperm fragment (covered by epilogue + next acc-init)
    if (t + 1 < T_){
      const ushort_t* gp = gp0 + (long)(t+1)*131072;
      #pragma unroll
      for (int ti = 0; ti < 8; ti++) gbuf[ti] = *(const short4v*)(const void*)(gp + ti*256);
    }
    // epilogue: gates -> h(t) -> h8[(t+1)&1] (fp8)
    #pragma unroll
    for (int jtI = 0; jtI < 2; jtI++){
      int j = (w + jtI*8)*16 + u;
      #pragma unroll
      for (int r = 0; r < 4; r++){
        float iv = fsig (acc[0+jtI][r]);
        float fv = fsig (acc[2+jtI][r]);
        float gv = ftanh(acc[4+jtI][r]);
        float ov = fsig (acc[6+jtI][r]);
        float c  = fv * c_reg[jtI][r] + iv * gv;
        c_reg[jtI][r] = c;
        float h  = ov * ftanh(c);
        int row = quad*4 + r;
        int p8 = __builtin_amdgcn_cvt_pk_fp8_f32(h, h, 0, false);
        h8[(t+1)&1][row][j] = (char)(p8 & 0xff);
      }
    }
  }
  __syncthreads();
  // final dump: h(511) lives in h8[0]
  {
    ushort_t* vrow = vbf + ((long)(T_-1) * B_ + bg*16) * 768;
    #pragma unroll
    for (int rr = 0; rr < 2; rr++){
      int row = w*2 + rr;
      uint32 p = *(const uint32*)(const void*)&h8[0][row][lane*4];
      float2v lo = __builtin_amdgcn_cvt_pk_f32_fp8(p, false);
      float2v hi = __builtin_amdgcn_cvt_pk_f32_fp8(p, true);
      short4v pk;
      pk[0] = (short)f2bf(lo[0]); pk[1] = (short)f2bf(lo[1]);
      pk[2] = (short)f2bf(hi[0]); pk[3] = (short)f2bf(hi[1]);
      *(short4v*)(void*)&vrow[(long)row*768 + lane*4] = pk;
    }
  }
}

extern "C" void kernel_launch(void* const* d_in, const int* in_sizes, int n_in,
                              void* d_out, int out_size, void* d_ws, size_t ws_size,
                              hipStream_t stream){
  (void)in_sizes; (void)n_in; (void)out_size; (void)ws_size;
  const float* enc     = (const float*)d_in[0];
  const int*   sep     = (const int*)  d_in[1];
  const int*   pos_ids = (const int*)  d_in[2];
  const int*   len     = (const int*)  d_in[3];
  const float* pos_emb = (const float*)d_in[4];
  const float* wl_emb  = (const float*)d_in[5];
  const float* fcW     = (const float*)d_in[6];
  const float* fcb     = (const float*)d_in[7];
  const float* W_ih    = (const float*)d_in[8];
  const float* W_hh    = (const float*)d_in[9];
  const float* b_ih    = (const float*)d_in[10];
  const float* b_hh    = (const float*)d_in[11];
  const float* combW   = (const float*)d_in[12];

  char* ws = (char*)d_ws;
  int*      ls    = (int*)     (ws + OFF_LS);
  int*      lp    = (int*)     (ws + OFF_LP);
  int*      wid   = (int*)     (ws + OFF_WID);
  float*    inv   = (float*)   (ws + OFF_INV);
  float*    posW  = (float*)   (ws + OFF_POSW);
  float*    wlW   = (float*)   (ws + OFF_WLW);
  float*    biasg = (float*)   (ws + OFF_BIASG);
  char*     whh8  = (char*)    (ws + OFF_WHH);
  ushort_t* wih   = (ushort_t*)(ws + OFF_WIH);
  ushort_t* wenc  = (ushort_t*)(ws + OFF_WENC);
  ushort_t* combwb= (ushort_t*)(ws + OFF_COMBW);
  ushort_t* ecw   = (ushort_t*)(ws + OFF_ECW);
  ushort_t* zbf   = (ushort_t*)(ws + OFF_Z);
  ushort_t* gperm = (ushort_t*)(ws + OFF_GPERM);
  ushort_t* vbf   = (ushort_t*)(ws + OFF_VBF);

  k_scan<<<2, 64, 0, stream>>>(sep, pos_ids, ls, lp, wid, inv);
  k_encbf<<<BT_, 256, 0, stream>>>(enc, vbf);
  k_small<<<2530, 256, 0, stream>>>(pos_emb, wl_emb, fcW, W_ih, W_hh, b_ih, b_hh, combW,
                                    posW, wlW, biasg, whh8, wih, wenc, combwb);
  // E = enc @ Wenc^T  (rows time-major)
  k_gemm<0><<<dim3(BT_/64, 4), 256, 0, stream>>>(vbf + 256, 768L, wenc, 512, LIN_, ecw, nullptr, nullptr);
  // exclusive cumsum over t (in place) -> CW
  k_cum200<<<B_, 256, 0, stream>>>(ecw);
  // z = tanh(...)
  k_z<<<BT_, 256, 0, stream>>>(ecw, ls, lp, wid, inv, posW, wlW, fcb, zbf);
  // Gperm = z @ W_ih^T + biases, written pre-swizzled for k_rec
  k_gemm<1><<<dim3(BT_/64, 16), 256, 0, stream>>>(zbf, (long)LINP_, wih, LINP_, G4_, gperm, biasg, nullptr);
  // LSTM recurrence (8 independent batch-group workgroups, LDS-only sync)
  k_rec<<<8, 512, 0, stream>>>(gperm, whh8, vbf);
  // logits = [hs, enc] @ combine_W^T, masked, scattered to b-major output
  k_gemm<2><<<dim3(BT_/64, 1), 256, 0, stream>>>(vbf, 768L, combwb, 768, SP_, d_out, nullptr, len);
}

// Round 6
// 1374.046 us; speedup vs baseline: 1.2157x; 1.0665x over previous
//
#include <hip/hip_runtime.h>

typedef unsigned short ushort_t;
typedef unsigned int uint32;
typedef __attribute__((ext_vector_type(8))) short short8;
typedef __attribute__((ext_vector_type(4))) short short4v;
typedef __attribute__((ext_vector_type(4))) float floatx4;
typedef __attribute__((ext_vector_type(2))) float float2v;
typedef __attribute__((ext_vector_type(8))) int intx8;

#define B_    128
#define T_    512
#define H_    256
#define H2_   512
#define LIN_  200
#define LINP_ 224
#define G4_   1024
#define SP_   58
#define BT_   (B_*T_)

// ---------- ws layout (bytes) ----------
#define OFF_LS     0UL          // int  [B,T]      262144
#define OFF_LP     262144UL     // int  [B,T]      262144
#define OFF_WID    524288UL     // int  [B,T]      262144
#define OFF_INV    786432UL     // f32  [B,T]      262144
#define OFF_POSW   1212416UL    // f32  [32][200]   25600
#define OFF_WLW    1238016UL    // f32  [8][200]     6400
#define OFF_BIASG  1244416UL    // f32  [1024]       4096
#define OFF_WHH    1248512UL    // fp8  [1024][256] 262144
#define OFF_WIH    1772800UL    // bf16 [1024][224] 458752
#define OFF_WENC   2231552UL    // bf16 [200][512]  204800
#define OFF_COMBW  2436352UL    // bf16 [58][768]    89088
#define OFF_ECW    2525440UL    // bf16 [65536][200] time-major rows (t*128+b)
#define OFF_Z      28739840UL   // bf16 [65536][224] time-major rows
#define OFF_GPERM  58099968UL   // bf16 swizzled [512][8][16][4][64][4]
#define OFF_VBF    192317696UL  // bf16 [65536][768] time-major rows (0:256 hs, 256:768 enc)

__device__ __forceinline__ ushort_t f2bf(float x){
  uint32 u = __float_as_uint(x);
  u += 0x7fffu + ((u >> 16) & 1u);
  return (ushort_t)(u >> 16);
}
__device__ __forceinline__ float bf2f(ushort_t v){
  return __uint_as_float(((uint32)v) << 16);
}
// fast sigmoid/tanh (exp2-based __expf + v_rcp); |err| ~1e-5, way inside bf16
__device__ __forceinline__ float fsig(float x){
  return __builtin_amdgcn_rcpf(1.0f + __expf(-x));
}
__device__ __forceinline__ float ftanh(float x){
  return 1.0f - 2.0f * __builtin_amdgcn_rcpf(1.0f + __expf(2.0f * x));
}

// ---------- scan: last_sep / wordlen / last_pos (b-major aux arrays) ----------
__global__ void k_scan(const int* __restrict__ sep, const int* __restrict__ pos_ids,
                       int* __restrict__ ls, int* __restrict__ lp,
                       int* __restrict__ wid, float* __restrict__ inv){
  int b = blockIdx.x * 64 + threadIdx.x;
  if (b >= B_) return;
  int run = 0;
  for (int t = 0; t < T_; t++){
    int l = (t == 0) ? 0 : run;
    if (sep[b*T_ + t] > 0) run = t;
    int wlen = t - l;
    int wsv  = (wlen < 1) ? 1 : wlen;
    ls[b*T_ + t]  = l;
    lp[b*T_ + t]  = pos_ids[b*T_ + l];
    wid[b*T_ + t] = (wsv > 7) ? 7 : wsv;
    inv[b*T_ + t] = 1.0f / (float)wsv;
  }
}

// ---------- enc -> bf16 into vbf[t*128+b][256:768] ----------
__global__ __launch_bounds__(256) void k_encbf(const float* __restrict__ enc, ushort_t* __restrict__ vbf){
  long row = blockIdx.x;           // b*512 + t (matches enc layout)
  int b = (int)(row >> 9), t = (int)(row & (T_-1));
  int c = threadIdx.x;
  const float* e = enc + row * H2_;
  ushort_t* v = vbf + ((long)t * B_ + b) * 768 + 256;
  v[c]       = f2bf(e[c]);
  v[c + 256] = f2bf(e[c + 256]);
}

// ---------- small precomputes / weight conversions ----------
__global__ __launch_bounds__(256) void k_small(
    const float* __restrict__ pos_emb, const float* __restrict__ wl_emb,
    const float* __restrict__ fcW, const float* __restrict__ W_ih,
    const float* __restrict__ W_hh, const float* __restrict__ b_ih,
    const float* __restrict__ b_hh, const float* __restrict__ combW,
    float* __restrict__ posW, float* __restrict__ wlW, float* __restrict__ biasg,
    char* __restrict__ whh8, ushort_t* __restrict__ wih,
    ushort_t* __restrict__ wenc, ushort_t* __restrict__ combwb){
  int idx = blockIdx.x * 256 + threadIdx.x;
  if (idx < 6400){
    int p = idx / 200, l = idx % 200;
    float s = 0.f;
    for (int d = 0; d < 50; d++) s += pos_emb[p*50 + d] * fcW[l*582 + d];
    posW[idx] = s; return;
  }
  idx -= 6400;
  if (idx < 1600){
    int w = idx / 200, l = idx % 200;
    float s = 0.f;
    for (int d = 0; d < 20; d++) s += wl_emb[w*20 + d] * fcW[l*582 + 562 + d];
    wlW[idx] = s; return;
  }
  idx -= 1600;
  if (idx < 1024){ biasg[idx] = b_ih[idx] + b_hh[idx]; return; }
  idx -= 1024;
  if (idx < 262144){
    int p8 = __builtin_amdgcn_cvt_pk_fp8_f32(W_hh[idx], W_hh[idx], 0, false);
    whh8[idx] = (char)(p8 & 0xff);
    return;
  }
  idx -= 262144;
  if (idx < 229376){
    int n = idx / 224, k = idx % 224;
    wih[idx] = (k < 200) ? f2bf(W_ih[n*200 + k]) : (ushort_t)0;
    return;
  }
  idx -= 229376;
  if (idx < 102400){
    int l = idx / 512, c = idx % 512;
    wenc[idx] = f2bf(fcW[l*582 + 50 + c]); return;
  }
  idx -= 102400;
  if (idx < 44544){ combwb[idx] = f2bf(combW[idx]); return; }
}

// ---------- generic 64x64 bf16 MFMA GEMM: C[m,n] = sum_k A[m,k]*B[n,k] ----------
// EPI 0: bf16 out [m][Nvalid]
// EPI 1: +bias, bf16 out swizzled Gperm fragment layout [t][bg][jt][g][lane][r]
// EPI 2: masked fp32 logits, m time-major -> out b-major [b*T+t][58]
template<int EPI>
__global__ __launch_bounds__(256) void k_gemm(
    const ushort_t* __restrict__ A, long lda,
    const ushort_t* __restrict__ Bm, int K, int Nvalid,
    void* __restrict__ Cout, const float* __restrict__ bias, const int* __restrict__ len){
  __shared__ __attribute__((aligned(16))) ushort_t As[64][48];
  __shared__ __attribute__((aligned(16))) ushort_t Bs[64][48];
  int tid  = threadIdx.x;
  int lane = tid & 63, wave = tid >> 6;
  int u = lane & 15, quad = lane >> 4;
  int mh = wave >> 1, nh = wave & 1;
  long m0 = (long)blockIdx.x * 64;
  int  n0 = blockIdx.y * 64;
  int lrow = tid >> 2;
  int lcol = (tid & 3) * 8;
  const ushort_t* Arow = A + (m0 + lrow) * lda + lcol;
  bool bvalid = (n0 + lrow) < Nvalid;
  const ushort_t* Brow = Bm + (long)(n0 + lrow) * K + lcol;
  floatx4 acc[2][2] = {};
  for (int k = 0; k < K; k += 32){
    short8 av = *(const short8*)(const void*)(Arow + k);
    short8 bv = {0,0,0,0,0,0,0,0};
    if (bvalid) bv = *(const short8*)(const void*)(Brow + k);
    __syncthreads();
    *(short8*)(void*)&As[lrow][lcol] = av;
    *(short8*)(void*)&Bs[lrow][lcol] = bv;
    __syncthreads();
    short8 a0 = *(const short8*)(const void*)&As[mh*32 + u][quad*8];
    short8 a1 = *(const short8*)(const void*)&As[mh*32 + 16 + u][quad*8];
    short8 b0 = *(const short8*)(const void*)&Bs[nh*32 + u][quad*8];
    short8 b1 = *(const short8*)(const void*)&Bs[nh*32 + 16 + u][quad*8];
    acc[0][0] = __builtin_amdgcn_mfma_f32_16x16x32_bf16(a0, b0, acc[0][0], 0, 0, 0);
    acc[0][1] = __builtin_amdgcn_mfma_f32_16x16x32_bf16(a0, b1, acc[0][1], 0, 0, 0);
    acc[1][0] = __builtin_amdgcn_mfma_f32_16x16x32_bf16(a1, b0, acc[1][0], 0, 0, 0);
    acc[1][1] = __builtin_amdgcn_mfma_f32_16x16x32_bf16(a1, b1, acc[1][1], 0, 0, 0);
  }
  if (EPI == 1){
    #pragma unroll
    for (int mi = 0; mi < 2; mi++){
      #pragma unroll
      for (int ni = 0; ni < 2; ni++){
        long mm = m0 + mh*32 + mi*16 + quad*4;     // r=0 row; 4 r's = 4 consecutive b
        int n = n0 + nh*32 + ni*16 + u;
        float bv = bias[n];
        int t = (int)(mm >> 7);
        int b = (int)(mm & 127);
        int bg = b >> 4, q2 = (b >> 2) & 3;
        int g = n >> 8, j = n & 255, uu = j & 15, jt = j >> 4;
        long idx = ((((long)t*8 + bg)*16 + jt)*4 + g)*256 + (q2*16 + uu)*4;
        short4v pk;
        #pragma unroll
        for (int r = 0; r < 4; r++) pk[r] = (short)f2bf(acc[mi][ni][r] + bv);
        *(short4v*)(void*)((ushort_t*)Cout + idx) = pk;
      }
    }
  } else {
    for (int mi = 0; mi < 2; mi++){
      for (int ni = 0; ni < 2; ni++){
        for (int r = 0; r < 4; r++){
          long m = m0 + mh*32 + mi*16 + quad*4 + r;
          int  n = n0 + nh*32 + ni*16 + u;
          float v = acc[mi][ni][r];
          if (EPI == 0){
            if (n < Nvalid) ((ushort_t*)Cout)[m * Nvalid + n] = f2bf(v);
          } else {
            if (n < Nvalid){
              int t = (int)(m >> 7); int b = (int)(m & 127);
              float o = (t < len[b]) ? v : 0.0f;
              if (t == 0 && n == 0) o = -1e30f;
              ((float*)Cout)[((long)b * T_ + t) * SP_ + n] = o;
            }
          }
        }
      }
    }
  }
}

// ---------- exclusive cumsum over t, in place on E (bf16, time-major rows) ----------
__global__ __launch_bounds__(256) void k_cum200(ushort_t* __restrict__ E){
  int b = blockIdx.x;
  int c = threadIdx.x;
  if (c >= LIN_) return;
  float acc = 0.f;
  ushort_t* p = E + (long)b * LIN_ + c;      // row (t*128+b)
  const long rs = (long)B_ * LIN_;           // per-t stride
  for (int t0 = 0; t0 < T_; t0 += 16){
    float vv[16];
    #pragma unroll
    for (int i = 0; i < 16; i++) vv[i] = bf2f(p[i*rs]);
    #pragma unroll
    for (int i = 0; i < 16; i++){ p[i*rs] = f2bf(acc); acc += vv[i]; }
    p += 16*rs;
  }
}

// ---------- z = tanh((CW[t]-CW[ls])*inv + posW + wlW + b), t=0 -> 0, pad K to 224 ----------
__global__ __launch_bounds__(256) void k_z(
    const ushort_t* __restrict__ CW, const int* __restrict__ ls, const int* __restrict__ lp,
    const int* __restrict__ wid, const float* __restrict__ inv,
    const float* __restrict__ posW, const float* __restrict__ wlW,
    const float* __restrict__ fcb, ushort_t* __restrict__ zbf){
  int m = blockIdx.x;               // time-major row t*128+b
  int l = threadIdx.x;
  if (l >= LINP_) return;
  int t = m >> 7;
  int b = m & 127;
  int ar = b * T_ + t;              // b-major aux index
  ushort_t o = 0;
  if (t != 0 && l < LIN_){
    int lsv = ls[ar];
    float x = bf2f(CW[(long)m * LIN_ + l]) - bf2f(CW[((long)lsv * B_ + b) * LIN_ + l]);
    x = x * inv[ar] + posW[lp[ar]*LIN_ + l] + wlW[wid[ar]*LIN_ + l] + fcb[l];
    o = f2bf(ftanh(x));
  }
  zbf[(long)m * LINP_ + l] = o;
}

// ---------- LSTM recurrence: 8 blocks x 1024 threads (16 waves, 4/SIMD) ----------
// Wave w owns hidden j-tile w (16 units) across all 4 gates: 4 col tiles, 8 MX MFMAs.
// 4 outputs/lane -> half the per-wave epilogue VALU; 4 waves/SIMD hide exp-chain latency.
// h via fp8 LDS double buffer, single __syncthreads per step; coalesced delayed vbf dump.
__global__ __launch_bounds__(1024, 4) void k_rec(
    const ushort_t* __restrict__ Gperm, const char* __restrict__ whh8,
    ushort_t* __restrict__ vbf){
  int bg   = blockIdx.x;
  int tid  = threadIdx.x;
  int lane = tid & 63, w = tid >> 6;          // w in [0,16): hidden j-tile
  int u = lane & 15, quad = lane >> 4;
  __shared__ __attribute__((aligned(16))) char h8[2][16][272];   // row stride 272
  for (int i = tid; i < (int)(sizeof(h8)/4); i += 1024) ((int*)h8)[i] = 0;

  // W_hh fp8 B-fragments (MX K=128): gate g, cols w*16+u; pinned in VGPRs.
  intx8 wfx[4][2];
  #pragma unroll
  for (int g = 0; g < 4; g++){
    int grow = g*256 + w*16 + u;
    #pragma unroll
    for (int kc = 0; kc < 2; kc++){
      intx8 v = *(const intx8*)(const void*)(whh8 + (long)grow*256 + kc*128 + quad*32);
      asm volatile("" : "+v"(v));
      wfx[g][kc] = v;
    }
  }
  float c_reg[4] = {0.f, 0.f, 0.f, 0.f};

  const ushort_t* gp0 = Gperm + ((long)bg*16 + w)*1024 + (long)lane*4;
  short4v gbuf[4];
  #pragma unroll
  for (int g = 0; g < 4; g++) gbuf[g] = *(const short4v*)(const void*)(gp0 + g*256);

  for (int t = 0; t < T_; t++){
    floatx4 acc[4];
    #pragma unroll
    for (int g = 0; g < 4; g++){
      #pragma unroll
      for (int r = 0; r < 4; r++)
        acc[g][r] = bf2f((ushort_t)gbuf[g][r]);
    }
    __syncthreads();                       // h8[t&1] = h(t-1) ready
    intx8 af0 = *(const intx8*)(const void*)&h8[t & 1][u][quad*32];
    intx8 af1 = *(const intx8*)(const void*)&h8[t & 1][u][128 + quad*32];
    #pragma unroll
    for (int g = 0; g < 4; g++){
      acc[g] = __builtin_amdgcn_mfma_scale_f32_16x16x128_f8f6f4(
          af0, wfx[g][0], acc[g], 0, 0, 0, 0x7F7F7F7F, 0, 0x7F7F7F7F);
      acc[g] = __builtin_amdgcn_mfma_scale_f32_16x16x128_f8f6f4(
          af1, wfx[g][1], acc[g], 0, 0, 0, 0x7F7F7F7F, 0, 0x7F7F7F7F);
    }
    // coalesced vbf dump of h(t-1) row w (hides under MFMA pipe)
    if (t){
      ushort_t* vrow = vbf + ((long)(t-1) * B_ + bg*16) * 768;
      uint32 p = *(const uint32*)(const void*)&h8[t & 1][w][lane*4];
      float2v lo = __builtin_amdgcn_cvt_pk_f32_fp8(p, false);
      float2v hi = __builtin_amdgcn_cvt_pk_f32_fp8(p, true);
      short4v pk;
      pk[0] = (short)f2bf(lo[0]); pk[1] = (short)f2bf(lo[1]);
      pk[2] = (short)f2bf(hi[0]); pk[3] = (short)f2bf(hi[1]);
      *(short4v*)(void*)&vrow[(long)w*768 + lane*4] = pk;
    }
    // prefetch next Gperm fragment
    if (t + 1 < T_){
      const ushort_t* gp = gp0 + (long)(t+1)*131072;
      #pragma unroll
      for (int g = 0; g < 4; g++) gbuf[g] = *(const short4v*)(const void*)(gp + g*256);
    }
    // epilogue: gates -> h(t) -> h8[(t+1)&1] (fp8); lane owns j = w*16+u, rows quad*4+r
    int j = w*16 + u;
    #pragma unroll
    for (int r = 0; r < 4; r++){
      float iv = fsig (acc[0][r]);
      float fv = fsig (acc[1][r]);
      float gv = ftanh(acc[2][r]);
      float ov = fsig (acc[3][r]);
      float c  = fv * c_reg[r] + iv * gv;
      c_reg[r] = c;
      float h  = ov * ftanh(c);
      int row = quad*4 + r;
      int p8 = __builtin_amdgcn_cvt_pk_fp8_f32(h, h, 0, false);
      h8[(t+1)&1][row][j] = (char)(p8 & 0xff);
    }
  }
  __syncthreads();
  // final dump: h(511) lives in h8[0]
  {
    ushort_t* vrow = vbf + ((long)(T_-1) * B_ + bg*16) * 768;
    uint32 p = *(const uint32*)(const void*)&h8[0][w][lane*4];
    float2v lo = __builtin_amdgcn_cvt_pk_f32_fp8(p, false);
    float2v hi = __builtin_amdgcn_cvt_pk_f32_fp8(p, true);
    short4v pk;
    pk[0] = (short)f2bf(lo[0]); pk[1] = (short)f2bf(lo[1]);
    pk[2] = (short)f2bf(hi[0]); pk[3] = (short)f2bf(hi[1]);
    *(short4v*)(void*)&vrow[(long)w*768 + lane*4] = pk;
  }
}

extern "C" void kernel_launch(void* const* d_in, const int* in_sizes, int n_in,
                              void* d_out, int out_size, void* d_ws, size_t ws_size,
                              hipStream_t stream){
  (void)in_sizes; (void)n_in; (void)out_size; (void)ws_size;
  const float* enc     = (const float*)d_in[0];
  const int*   sep     = (const int*)  d_in[1];
  const int*   pos_ids = (const int*)  d_in[2];
  const int*   len     = (const int*)  d_in[3];
  const float* pos_emb = (const float*)d_in[4];
  const float* wl_emb  = (const float*)d_in[5];
  const float* fcW     = (const float*)d_in[6];
  const float* fcb     = (const float*)d_in[7];
  const float* W_ih    = (const float*)d_in[8];
  const float* W_hh    = (const float*)d_in[9];
  const float* b_ih    = (const float*)d_in[10];
  const float* b_hh    = (const float*)d_in[11];
  const float* combW   = (const float*)d_in[12];

  char* ws = (char*)d_ws;
  int*      ls    = (int*)     (ws + OFF_LS);
  int*      lp    = (int*)     (ws + OFF_LP);
  int*      wid   = (int*)     (ws + OFF_WID);
  float*    inv   = (float*)   (ws + OFF_INV);
  float*    posW  = (float*)   (ws + OFF_POSW);
  float*    wlW   = (float*)   (ws + OFF_WLW);
  float*    biasg = (float*)   (ws + OFF_BIASG);
  char*     whh8  = (char*)    (ws + OFF_WHH);
  ushort_t* wih   = (ushort_t*)(ws + OFF_WIH);
  ushort_t* wenc  = (ushort_t*)(ws + OFF_WENC);
  ushort_t* combwb= (ushort_t*)(ws + OFF_COMBW);
  ushort_t* ecw   = (ushort_t*)(ws + OFF_ECW);
  ushort_t* zbf   = (ushort_t*)(ws + OFF_Z);
  ushort_t* gperm = (ushort_t*)(ws + OFF_GPERM);
  ushort_t* vbf   = (ushort_t*)(ws + OFF_VBF);

  k_scan<<<2, 64, 0, stream>>>(sep, pos_ids, ls, lp, wid, inv);
  k_encbf<<<BT_, 256, 0, stream>>>(enc, vbf);
  k_small<<<2530, 256, 0, stream>>>(pos_emb, wl_emb, fcW, W_ih, W_hh, b_ih, b_hh, combW,
                                    posW, wlW, biasg, whh8, wih, wenc, combwb);
  // E = enc @ Wenc^T  (rows time-major)
  k_gemm<0><<<dim3(BT_/64, 4), 256, 0, stream>>>(vbf + 256, 768L, wenc, 512, LIN_, ecw, nullptr, nullptr);
  // exclusive cumsum over t (in place) -> CW
  k_cum200<<<B_, 256, 0, stream>>>(ecw);
  // z = tanh(...)
  k_z<<<BT_, 256, 0, stream>>>(ecw, ls, lp, wid, inv, posW, wlW, fcb, zbf);
  // Gperm = z @ W_ih^T + biases, written pre-swizzled for k_rec ([t][bg][jt][g][lane][r])
  k_gemm<1><<<dim3(BT_/64, 16), 256, 0, stream>>>(zbf, (long)LINP_, wih, LINP_, G4_, gperm, biasg, nullptr);
  // LSTM recurrence (8 blocks x 16 waves, LDS-only sync)
  k_rec<<<8, 1024, 0, stream>>>(gperm, whh8, vbf);
  // logits = [hs, enc] @ combine_W^T, masked, scattered to b-major output
  k_gemm<2><<<dim3(BT_/64, 1), 256, 0, stream>>>(vbf, 768L, combwb, 768, SP_, d_out, nullptr, len);
}